// Round 17
// baseline (182.502 us; speedup 1.0000x reference)
//
#include <hip/hip_runtime.h>
#include <stdint.h>

typedef int v4i __attribute__((ext_vector_type(4)));
typedef int v16i __attribute__((ext_vector_type(16)));

#define GLDS16(gsrc, ldst) __builtin_amdgcn_global_load_lds( \
    (const __attribute__((address_space(1))) void*)(gsrc),   \
    (__attribute__((address_space(3))) void*)(ldst), 16, 0, 0)

// dims: B=16, C=256, H=W=56, padded 58x58, NPIX=50176
// XCD plan (8 XCDs, linear-dispatch round-robin bid%8): xcd owns images {2*xcd, 2*xcd+1}
// across signx -> conv1 -> conv2 -> final, so halo + producer->consumer reads are L2-local.

// ---------------- launch 1: hyper + bias-prep + sums-zero + signx, one dispatch ----------------
// bid<512: hyper (set=bid>>8, oi=bid&255); 512-543: bias; 544: zero sums; 545+: signx.
// fc2: 8 chunks x 128 rows (32KB), 2 threads/row (col halves), LDS partial combine.
// fc3: W3 staged in 2 ROW-halves (72 rows); output computed wholly in its row's pass.
// WbP layout: chunk = (tap*4 + c64)*2 + c2 ; addr = chunk*8192 + co*32 + (ci&31)

__global__ __launch_bounds__(256, 3) void fused_pre_kernel(
    const float* __restrict__ z1, const float* __restrict__ W21,
    const float* __restrict__ W31, const float* __restrict__ z2,
    const float* __restrict__ W22, const float* __restrict__ W32,
    int8_t* __restrict__ Wb1, int8_t* __restrict__ Wb2,
    const float* __restrict__ W01, const float* __restrict__ W02,
    int* __restrict__ b1, int* __restrict__ b2,
    unsigned long long* __restrict__ sums,
    const float* __restrict__ x, int8_t* __restrict__ Sp) {
  __shared__ __align__(16) float Wt[8192];    // 128 rows x 64 f (32KB); signx tile aliases
  __shared__ __align__(16) double pdot[256];  // fc2 partials (4KB)
  __shared__ __align__(16) double pnrm[256];
  __shared__ __align__(16) float hbuf[16 * 72];
  __shared__ __align__(16) float zsh[64];
  __shared__ __align__(16) int8_t pk[2304];
  const int tid = threadIdx.x;

  if (blockIdx.x >= 545) {                    // ---- signx: sign(x) -> padded NHWC ----
    const int fs = blockIdx.x - 545;          // [0,928)
    const int xcd = blockIdx.x & 7;           // actual XCD of this block
    const int orig = xcd * 116 + (fs >> 3);   // xcd X handles images 2X,2X+1 (116 rows)
    const int b = orig / 58, h = orig % 58;
    int8_t* rowp = Sp + ((size_t)b * 58 + h) * 58 * 256;
    if (h == 0 || h == 57) {
      #pragma unroll
      for (int i = 0; i < 4; ++i) {
        int idx = i * 256 + tid;
        if (idx < 928) *(v4i*)(rowp + (size_t)idx * 16) = (v4i){0, 0, 0, 0};
      }
      return;
    }
    int8_t* t = (int8_t*)Wt;                  // 56*256 = 14KB tile
    const float* xb = x + (size_t)b * 802816 + (size_t)(h - 1) * 56;
    for (int i = 0; i < 56; ++i) {
      int flat = i * 256 + tid;               // 14336 = 256c * 56w
      int c = flat / 56, w = flat - c * 56;
      float v = xb[(size_t)c * 3136 + w];
      t[w * 256 + (c ^ ((w & 31) << 3))] = (v > 0.f) ? 1 : ((v < 0.f) ? -1 : 0);
    }
    if (tid < 32) {   // zero cols 0 and 57
      int col = tid >> 4;
      *(v4i*)(rowp + (col ? 57 * 256 : 0) + (tid & 15) * 16) = (v4i){0, 0, 0, 0};
    }
    __syncthreads();
    int8_t* dst = rowp + 256;
    for (int i = 0; i < 7; ++i) {
      int f8 = i * 256 + tid;                 // 1792 8-byte chunks
      int w = f8 >> 5, c0 = (f8 & 31) << 3;
      uint2 v = *(const uint2*)&t[w * 256 + (c0 ^ ((w & 31) << 3))];
      *(uint2*)(dst + (size_t)w * 256 + c0) = v;
    }
    return;
  }

  if (blockIdx.x >= 512) {                    // ---- bias prep / zero sums ----
    const int pb = blockIdx.x - 512;
    if (pb == 32) {
      #pragma unroll
      for (int i = 0; i < 4; ++i) sums[i * 256 + tid] = 0ull;
      return;
    }
    float* zs = Wt;                           // reuse LDS (4KB)
    const int set = pb >> 4, o = pb & 15;
    const float* z = set ? z2 : z1;
    const float* W0 = set ? W02 : W01;
    int* bout = set ? b2 : b1;
    #pragma unroll
    for (int i = 0; i < 4; ++i) zs[i * 256 + tid] = z[(size_t)o * 1024 + i * 256 + tid];
    __syncthreads();
    const int j = tid >> 4, l = tid & 15;
    const float* wr = W0 + (size_t)j * 1024;
    double acc = 0.0;
    #pragma unroll 4
    for (int it = 0; it < 16; ++it) {
      float4 w4 = *(const float4*)&wr[it * 64 + l * 4];
      float4 z4 = *(const float4*)&zs[it * 64 + l * 4];
      acc += (double)w4.x * z4.x + (double)w4.y * z4.y + (double)w4.z * z4.z + (double)w4.w * z4.w;
    }
    #pragma unroll
    for (int m = 1; m < 16; m <<= 1) acc += __shfl_xor(acc, m, 64);
    if (l == 0) bout[o * 16 + j] = (acc > 0.0) ? 1 : ((acc < 0.0) ? -1 : 0);
    return;
  }

  // ---- hyper ----
  const int set = blockIdx.x >> 8;
  const int oi = blockIdx.x & 255;      // o*16+i
  const float* z = set ? z2 : z1;
  const float* W2 = set ? W22 : W21;
  const float* W3 = set ? W32 : W31;
  int8_t* Wb = set ? Wb2 : Wb1;

  if (tid < 16) *(float4*)&zsh[tid * 4] = ((const float4*)(z + (size_t)oi * 64))[tid];
  __syncthreads();

  // fc2: 8 chunks of 128 rows; thread (r=tid&127, half=tid>>7) does cols half*32..+31.
  {
    const int r = tid & 127, half = tid >> 7;
    for (int c = 0; c < 8; ++c) {
      if (c) __syncthreads();                 // combine of prev chunk done
      const float4* src = (const float4*)W2 + (size_t)c * 2048;
      #pragma unroll
      for (int i = 0; i < 8; ++i) {
        int G = i * 256 + tid;                // < 2048
        int row = G >> 4, g = G & 15;
        *(float4*)&Wt[row * 64 + (((g ^ row ^ (row >> 4)) & 15) << 2)] = src[G];
      }
      __syncthreads();
      double ax = 0, ay = 0, az = 0, aw = 0;
      double nx = 0, ny = 0, nz = 0, nw = 0;
      #pragma unroll
      for (int it = 0; it < 8; ++it) {
        int gi = half * 8 + it;
        float4 w4 = *(const float4*)&Wt[r * 64 + (((gi ^ r ^ (r >> 4)) & 15) << 2)];
        float4 z4 = *(const float4*)&zsh[gi * 4];
        ax += (double)w4.x * z4.x; ay += (double)w4.y * z4.y;
        az += (double)w4.z * z4.z; aw += (double)w4.w * z4.w;
        nx += (double)w4.x * w4.x; ny += (double)w4.y * w4.y;
        nz += (double)w4.z * w4.z; nw += (double)w4.w * w4.w;
      }
      pdot[tid] = (ax + ay) + (az + aw);
      pnrm[tid] = (nx + ny) + (nz + nw);
      __syncthreads();
      if (tid < 128) {
        double dot = pdot[tid] + pdot[tid + 128];
        double ss  = pnrm[tid] + pnrm[tid + 128];
        int j = c * 128 + tid;                // row index 0..1023 -> [q][e] padded 72
        hbuf[(j >> 6) * 72 + (j & 63)] = (float)(dot / sqrt(ss + 1e-6));
      }
    }
  }

  // fc3: W3 staged in 2 row-halves [72][64] (18.4KB); output (sub,k) computed in the
  // pass holding row jj = sub+16k. Single local f64 accumulator.
  {
    const int q = tid >> 4, sub = tid & 15;
    #pragma unroll
    for (int h = 0; h < 2; ++h) {
      __syncthreads();
      const float4* src = (const float4*)W3 + h * 1152;
      #pragma unroll
      for (int i = 0; i < 5; ++i) {
        int G = i * 256 + tid;
        if (G < 1152) {
          int lr = G >> 4, g = G & 15;
          *(float4*)&Wt[lr * 64 + (((g ^ lr ^ (lr >> 4)) & 15) << 2)] = src[G];
        }
      }
      __syncthreads();
      #pragma unroll
      for (int k = 0; k < 9; ++k) {
        int jj = sub + (k << 4);
        if (jj >= h * 72 && jj < h * 72 + 72) {
          int lr = jj - h * 72;
          double a = 0.0;
          #pragma unroll
          for (int it = 0; it < 16; ++it) {
            float4 w4 = *(const float4*)&Wt[lr * 64 + (((it ^ lr ^ (lr >> 4)) & 15) << 2)];
            float4 h4 = *(const float4*)&hbuf[q * 72 + it * 4];
            a += (double)w4.x * h4.x + (double)w4.y * h4.y
               + (double)w4.z * h4.z + (double)w4.w * h4.w;
          }
          int8_t sgn = (a > 0.0) ? (int8_t)1 : ((a < 0.0) ? (int8_t)(-1) : (int8_t)0);
          int tp = jj / 9, tap = jj - tp * 9;
          pk[tap * 256 + q * 16 + tp] = sgn;
        }
      }
    }
  }
  __syncthreads();

  // 144 coalesced 16B stores
  if (tid < 144) {
    const int tap = tid >> 4, qq = tid & 15;
    const int o = oi >> 4, ii = oi & 15;
    const int chunk = ((tap << 2) + (ii >> 2)) * 2 + ((ii >> 1) & 1);
    v4i val = *(const v4i*)&pk[tap * 256 + qq * 16];
    *(v4i*)(Wb + (size_t)chunk * 8192 + (size_t)(o * 16 + qq) * 32 + ((ii & 1) << 4)) = val;
  }
}

// ---------------- binarized 3x3 conv via i8 MFMA implicit GEMM ----------------
// grid (28,16), block 512 = 8 waves (pxgrp 0-1 x cogrp 0-3). Tile 112 px x 256 co.
// MODE0 stages B via global_load_lds (async DMA; pre-swizzled global source, linear
// LDS dest = wave-uniform base + lane*16). s_setprio(1) wraps the MFMA cluster (T5:
// no barriers in K-loop -> waves drift out of phase -> scheduler role diversity).
// MODE 1 computes BN1 thresholds per-block from sumsIn. XCD-swizzled.

template <int MODE>
__global__ __launch_bounds__(512, 4) void conv_kernel(
    const int8_t* __restrict__ Sp, const int16_t* __restrict__ rawin,
    const unsigned long long* __restrict__ sumsIn,
    const float* __restrict__ gamma, const float* __restrict__ beta,
    const int8_t* __restrict__ WbP, const int* __restrict__ bias,
    int16_t* __restrict__ raw, unsigned long long* __restrict__ sumsOut)
{
  __shared__ __align__(16) int8_t lds[59392];   // 232 pp-rows x 256B
  __shared__ float thrS[256];
  __shared__ int sfS[256];
  const int tid = threadIdx.x;
  const int lane = tid & 63;
  const int f0 = blockIdx.x + 28 * blockIdx.y;      // [0,448)
  const int orig = (f0 & 7) * 56 + (f0 >> 3);       // 448 = 8*56; xcd gets 2 images
  const int b = orig / 28, bx = orig % 28;
  const int H0 = bx << 1;             // output rows H0, H0+1

  const int n = lane & 31, kg = lane >> 5;
  const int wid = tid >> 6;
  const int cogrp = wid & 3, pxgrp = wid >> 2;

  if (MODE == 1) {                    // per-block BN1 threshold compute
    if (tid < 256) {
      double S = (double)(long long)sumsIn[tid];
      double Q = (double)(long long)sumsIn[256 + tid];
      double mean = S / 50176.0;
      double var = Q / 50176.0 - mean * mean;
      double istd = 1.0 / sqrt(var + 1e-5);
      double A = (double)gamma[tid] * istd;
      float Af = (float)A;
      float thr; int sf;
      if (Af > 0.f)      { thr = (float)(mean - (double)beta[tid] / A); sf = 1; }
      else if (Af < 0.f) { thr = (float)(mean - (double)beta[tid] / A); sf = -1; }
      else               { thr = -1e30f; sf = (beta[tid] > 0.f) ? 1 : ((beta[tid] < 0.f) ? -1 : 0); }
      thrS[tid] = thr; sfS[tid] = sf;
    }
    __syncthreads();
  }

  // ---- A prologue: chunk 0 into buf 0 ----
  const int8_t* Abase = WbP + (size_t)((cogrp << 6) + n) * 32 + (kg << 4);
  v4i Ar[2][2][2];   // [buf][c2][a]
  #pragma unroll
  for (int c2 = 0; c2 < 2; ++c2)
    #pragma unroll
    for (int a = 0; a < 2; ++a)
      Ar[0][c2][a] = *(const v4i*)(Abase + (size_t)c2 * 8192 + a * 1024);

  // ---- stage input tile: 232 pp x 16 granules, XOR-swizzled by col&7 ----
  if (MODE == 0) {
    // async global->LDS DMA: LDS dest linear (wave base + lane*16), source pre-swizzled
    const int8_t* SpB = Sp + ((size_t)b * 58 + H0) * 58 * 256;
    const int wavebase = wid << 6;
    #pragma unroll
    for (int it = 0; it < 8; ++it) {
      int Gw = it * 512 + wavebase;           // wave-uniform
      if (Gw < 3712) {                        // 3712 = 58 full wave-loads
        int G = Gw + lane;
        int pp = G >> 4, gl = G & 15;
        int wp = pp % 58;
        GLDS16(SpB + pp * 256 + ((gl ^ (wp & 7)) << 4), lds + (Gw << 4));
      }
    }
  } else {
    // threshold-binarize from raw i16: thread owns fixed ci-granule gsrc
    const int gsrc = tid & 15;
    const int ppt = tid >> 4;                 // 0..31
    float thr[16]; int sf[16];
    #pragma unroll
    for (int j = 0; j < 16; ++j) { thr[j] = thrS[gsrc * 16 + j]; sf[j] = sfS[gsrc * 16 + j]; }
    #pragma unroll
    for (int it = 0; it < 8; ++it) {
      int pp = it * 32 + ppt;
      if (pp < 232) {
        int prow = pp / 58, pcol = pp - prow * 58;
        int ir = H0 + prow - 1, ic = pcol - 1;
        v4i outv = (v4i){0, 0, 0, 0};
        if (ir >= 0 && ir <= 55 && ic >= 0 && ic <= 55) {
          const int16_t* src = rawin + ((size_t)(b * 3136 + ir * 56 + ic)) * 256 + gsrc * 16;
          v4i lo = *(const v4i*)src;
          v4i hi = *(const v4i*)(src + 8);
          #pragma unroll
          for (int j = 0; j < 16; ++j) {
            int wd = (j < 8) ? lo[(j >> 1) & 3] : hi[(j >> 1) & 3];
            int v = (j & 1) ? (wd >> 16) : (int)(short)wd;
            float fv = (float)v;
            int bj = (fv > thr[j]) ? sf[j] : ((fv < thr[j]) ? -sf[j] : 0);
            outv[j >> 2] |= (bj & 0xff) << ((j & 3) << 3);
          }
        }
        *(v4i*)(lds + ((pp << 4) + (gsrc ^ (pcol & 7))) * 16) = outv;
      }
    }
  }

  int pixoff[2], wcol[2];
  #pragma unroll
  for (int f = 0; f < 2; ++f) {
    int px = (((pxgrp << 1) + f) << 5) + n;
    if (px > 111) px = 111;       // wid=7,f=1,n>=16: clamped duplicate (not stored)
    int hh = px / 56, ww = px - hh * 56;
    pixoff[f] = hh * 58 + ww;
    wcol[f] = ww;
  }

  v16i acc[2][2];
  #pragma unroll
  for (int f = 0; f < 2; ++f)
    #pragma unroll
    for (int a = 0; a < 2; ++a)
      #pragma unroll
      for (int e = 0; e < 16; ++e) acc[f][a][e] = 0;

  __syncthreads();

  #pragma unroll
  for (int ks = 0; ks < 36; ++ks) {
    const int cur = ks & 1;
    if (ks + 1 < 36) {                    // depth-1 prefetch
      #pragma unroll
      for (int c2 = 0; c2 < 2; ++c2)
        #pragma unroll
        for (int a = 0; a < 2; ++a)
          Ar[cur ^ 1][c2][a] = *(const v4i*)(Abase + (size_t)((ks + 1) * 2 + c2) * 8192 + a * 1024);
    }
    const int tap = ks >> 2, c64 = ks & 3;
    const int r = tap / 3, s = tap - 3 * (tap / 3);
    __builtin_amdgcn_s_setprio(1);
    #pragma unroll
    for (int c2 = 0; c2 < 2; ++c2) {
      v4i Af0 = Ar[cur][c2][0], Af1 = Ar[cur][c2][1];
      #pragma unroll
      for (int f = 0; f < 2; ++f) {
        const int gb = (c64 << 2) + (c2 << 1) + kg;
        v4i Bf = *(const v4i*)(lds + ((pixoff[f] + r * 58 + s) << 8)
                               + ((gb ^ ((wcol[f] + s) & 7)) << 4));
        acc[f][0] = __builtin_amdgcn_mfma_i32_32x32x32_i8(Af0, Bf, acc[f][0], 0, 0, 0);
        acc[f][1] = __builtin_amdgcn_mfma_i32_32x32x32_i8(Af1, Bf, acc[f][1], 0, 0, 0);
      }
    }
    __builtin_amdgcn_s_setprio(0);
  }

  // ---- epilogue: acc+bias -> LDS repack (swizzled) -> coalesced stores + stats ----
  __syncthreads();                 // B-tile dead; reuse LDS
  #pragma unroll
  for (int f = 0; f < 2; ++f) {
    int px = (((pxgrp << 1) + f) << 5) + n;
    if (px < 112) {
      #pragma unroll
      for (int a = 0; a < 2; ++a) {
        #pragma unroll
        for (int q = 0; q < 4; ++q) {
          int co = (cogrp << 6) + (a << 5) + (q << 3) + (kg << 2);
          v4i bi = *(const v4i*)(bias + co);
          short4 o;
          o.x = (short)(acc[f][a][q * 4 + 0] + bi.x);
          o.y = (short)(acc[f][a][q * 4 + 1] + bi.y);
          o.z = (short)(acc[f][a][q * 4 + 2] + bi.z);
          o.w = (short)(acc[f][a][q * 4 + 3] + bi.w);
          int g = co >> 3;          // 0..31
          *(short4*)(lds + px * 512 + ((g ^ (px & 31)) << 4) + (kg << 3)) = o;
        }
      }
    }
  }
  __syncthreads();
  const int pbase = b * 3136 + bx * 112;
  const int gg = tid & 31;
  int s8[8], q8[8];
  #pragma unroll
  for (int j = 0; j < 8; ++j) { s8[j] = 0; q8[j] = 0; }
  #pragma unroll
  for (int i = 0; i < 7; ++i) {
    int rrow = i * 16 + (tid >> 5);
    v4i val = *(const v4i*)(lds + rrow * 512 + ((gg ^ (rrow & 31)) << 4));
    *(v4i*)(raw + (size_t)(pbase + rrow) * 256 + gg * 8) = val;
    #pragma unroll
    for (int j = 0; j < 8; ++j) {
      int wd = val[j >> 1];
      int v = (j & 1) ? (wd >> 16) : (int)(short)wd;
      s8[j] += v; q8[j] += v * v;
    }
  }
  __syncthreads();                 // done reading repack area
  int* red = (int*)lds;            // [0:4096) sums, [4096:8192) sq
  #pragma unroll
  for (int j = 0; j < 8; ++j) { red[tid * 8 + j] = s8[j]; red[4096 + tid * 8 + j] = q8[j]; }
  __syncthreads();
  if (tid < 256) {
    const int ch = tid;            // 256 channels
    const int own = ch >> 3, sub = ch & 7;
    long long S = 0, Q = 0;
    #pragma unroll
    for (int jj = 0; jj < 16; ++jj) {
      int t2 = own + 32 * jj;
      S += red[t2 * 8 + sub];
      Q += red[4096 + t2 * 8 + sub];
    }
    atomicAdd(&sumsOut[ch], (unsigned long long)S);
    atomicAdd(&sumsOut[256 + ch], (unsigned long long)Q);
  }
}

// ---------------- final: BN2 (params computed in-block) + residual, NHWC -> NCHW ----------------
// grid (56,16) remapped so xcd = b/2 (raw2 rows L2-local from conv2).

__global__ void final_kernel(const int16_t* __restrict__ raw2,
                             const unsigned long long* __restrict__ sums2,
                             const float* __restrict__ gamma, const float* __restrict__ beta,
                             const float* __restrict__ x, float* __restrict__ out) {
  __shared__ float t[256 * 57];
  __shared__ __align__(16) float mS[256], AS[256], bS[256];
  const int tid = threadIdx.x;
  const int f0 = blockIdx.x + 56 * blockIdx.y;      // [0,896)
  const int orig = (f0 & 7) * 112 + (f0 >> 3);      // 896 = 8*112
  const int b = orig / 56, h = orig % 56;
  const int rowp = b * 3136 + h * 56;
  {
    double S = (double)(long long)sums2[tid];
    double Q = (double)(long long)sums2[256 + tid];
    double mean = S / 50176.0;
    double var = Q / 50176.0 - mean * mean;
    double istd = 1.0 / sqrt(var + 1e-5);
    mS[tid] = (float)mean;
    AS[tid] = gamma[tid] * (float)istd;
    bS[tid] = beta[tid];
  }
  __syncthreads();
  for (int i = 0; i < 7; ++i) {
    int f8 = i * 256 + tid;
    int px = f8 >> 5, c0 = (f8 & 31) << 3;
    float m[8], A[8], bb[8];
    *(float4*)&m[0]  = *(const float4*)&mS[c0];
    *(float4*)&m[4]  = *(const float4*)&mS[c0 + 4];
    *(float4*)&A[0]  = *(const float4*)&AS[c0];
    *(float4*)&A[4]  = *(const float4*)&AS[c0 + 4];
    *(float4*)&bb[0] = *(const float4*)&bS[c0];
    *(float4*)&bb[4] = *(const float4*)&bS[c0 + 4];
    v4i vv = *(const v4i*)(raw2 + (size_t)(rowp + px) * 256 + c0);
    #pragma unroll
    for (int j = 0; j < 8; ++j) {
      int wd = vv[j >> 1];
      int v = (j & 1) ? (wd >> 16) : (int)(short)wd;
      t[(c0 + j) * 57 + px] = ((float)v - m[j]) * A[j] + bb[j];
    }
  }
  __syncthreads();
  const float* xb = x + (size_t)b * 802816 + (size_t)h * 56;
  float* ob = out + (size_t)b * 802816 + (size_t)h * 56;
  for (int i = 0; i < 16; ++i) {
    int idx = i * 256 + tid;            // 256c x 16 slots (14 valid)
    int c = idx >> 4, wq = idx & 15;
    if (wq < 14) {
      int w0 = wq * 4;
      float4 xv = *(const float4*)(xb + (size_t)c * 3136 + w0);
      float4 o;
      o.x = t[c * 57 + w0 + 0] + xv.x;
      o.y = t[c * 57 + w0 + 1] + xv.y;
      o.z = t[c * 57 + w0 + 2] + xv.z;
      o.w = t[c * 57 + w0 + 3] + xv.w;
      *(float4*)(ob + (size_t)c * 3136 + w0) = o;
    }
  }
}

// ---------------- host launcher ----------------

extern "C" void kernel_launch(void* const* d_in, const int* in_sizes, int n_in,
                              void* d_out, int out_size, void* d_ws, size_t ws_size,
                              hipStream_t stream) {
  const float* x      = (const float*)d_in[0];
  const float* z1     = (const float*)d_in[1];
  const float* W0_1   = (const float*)d_in[2];
  const float* W2_1   = (const float*)d_in[3];
  const float* W3_1   = (const float*)d_in[4];
  const float* gamma1 = (const float*)d_in[5];
  const float* beta1  = (const float*)d_in[6];
  const float* z2     = (const float*)d_in[7];
  const float* W0_2   = (const float*)d_in[8];
  const float* W2_2   = (const float*)d_in[9];
  const float* W3_2   = (const float*)d_in[10];
  const float* gamma2 = (const float*)d_in[11];
  const float* beta2  = (const float*)d_in[12];
  float* out = (float*)d_out;

  char* ws = (char*)d_ws;
  size_t off = 0;
  auto alloc = [&](size_t sz) -> void* {
    void* p = ws + off;
    off += (sz + 255) & ~(size_t)255;
    return p;
  };
  int8_t* Sp1   = (int8_t*)alloc(13778944);          // 16*58*58*256
  int16_t* raw1 = (int16_t*)alloc(25690112);         // 50176*256*2
  int16_t* raw2 = (int16_t*)alloc(25690112);
  int8_t* Wb1   = (int8_t*)alloc(589824);
  int8_t* Wb2   = (int8_t*)alloc(589824);
  int* b1       = (int*)alloc(1024);
  int* b2       = (int*)alloc(1024);
  unsigned long long* sums = (unsigned long long*)alloc(8192); // sums1 | sums2
  if (ws_size < off) return;

  fused_pre_kernel<<<1473, 256, 0, stream>>>(z1, W2_1, W3_1, z2, W2_2, W3_2, Wb1, Wb2,
                                             W0_1, W0_2, b1, b2, sums, x, Sp1);
  conv_kernel<0><<<dim3(28, 16), 512, 0, stream>>>(Sp1, nullptr, nullptr, nullptr, nullptr,
                                                   Wb1, b1, raw1, sums);
  conv_kernel<1><<<dim3(28, 16), 512, 0, stream>>>(nullptr, raw1, sums, gamma1, beta1,
                                                   Wb2, b2, raw2, sums + 512);
  final_kernel<<<dim3(56, 16), 256, 0, stream>>>(raw2, sums + 512, gamma2, beta2, x, out);
}

// Round 18
// 158.679 us; speedup vs baseline: 1.1501x; 1.1501x over previous
//
#include <hip/hip_runtime.h>
#include <stdint.h>

typedef int v4i __attribute__((ext_vector_type(4)));
typedef int v16i __attribute__((ext_vector_type(16)));

// dims: B=16, C=256, H=W=56, padded 58x58, NPIX=50176
// XCD plan (8 XCDs, linear-dispatch round-robin bid%8): xcd owns images {2*xcd, 2*xcd+1}
// across signx -> conv1 -> conv2 -> final, so halo + producer->consumer reads are L2-local.
// ROUND 18 = ROUND 16 verbatim (best measured: 158.75us). Round 17's global_load_lds +
// s_setprio additions both regressed (scratch-spill signature, +24us) and are reverted.

// ---------------- launch 1: hyper + bias-prep + sums-zero + signx, one dispatch ----------------
// bid<512: hyper (set=bid>>8, oi=bid&255); 512-543: bias; 544: zero sums; 545+: signx.
// fc2: 8 chunks x 128 rows (32KB), 2 threads/row (col halves), LDS partial combine ->
//   NO persistent per-thread arrays (rounds 13/15 spilled on those).
// fc3: W3 staged in 2 ROW-halves (72 rows, 18.4KB); each output computed wholly in the
//   pass holding its row -> single local f64. LDS ~44KB -> 3 blocks/CU.
// WbP layout: chunk = (tap*4 + c64)*2 + c2 ; addr = chunk*8192 + co*32 + (ci&31)

__global__ __launch_bounds__(256, 3) void fused_pre_kernel(
    const float* __restrict__ z1, const float* __restrict__ W21,
    const float* __restrict__ W31, const float* __restrict__ z2,
    const float* __restrict__ W22, const float* __restrict__ W32,
    int8_t* __restrict__ Wb1, int8_t* __restrict__ Wb2,
    const float* __restrict__ W01, const float* __restrict__ W02,
    int* __restrict__ b1, int* __restrict__ b2,
    unsigned long long* __restrict__ sums,
    const float* __restrict__ x, int8_t* __restrict__ Sp) {
  __shared__ __align__(16) float Wt[8192];    // 128 rows x 64 f (32KB); signx tile aliases
  __shared__ __align__(16) double pdot[256];  // fc2 partials (4KB)
  __shared__ __align__(16) double pnrm[256];
  __shared__ __align__(16) float hbuf[16 * 72];
  __shared__ __align__(16) float zsh[64];
  __shared__ __align__(16) int8_t pk[2304];
  const int tid = threadIdx.x;

  if (blockIdx.x >= 545) {                    // ---- signx: sign(x) -> padded NHWC ----
    const int fs = blockIdx.x - 545;          // [0,928)
    const int xcd = blockIdx.x & 7;           // actual XCD of this block
    const int orig = xcd * 116 + (fs >> 3);   // xcd X handles images 2X,2X+1 (116 rows)
    const int b = orig / 58, h = orig % 58;
    int8_t* rowp = Sp + ((size_t)b * 58 + h) * 58 * 256;
    if (h == 0 || h == 57) {
      #pragma unroll
      for (int i = 0; i < 4; ++i) {
        int idx = i * 256 + tid;
        if (idx < 928) *(v4i*)(rowp + (size_t)idx * 16) = (v4i){0, 0, 0, 0};
      }
      return;
    }
    int8_t* t = (int8_t*)Wt;                  // 56*256 = 14KB tile
    const float* xb = x + (size_t)b * 802816 + (size_t)(h - 1) * 56;
    for (int i = 0; i < 56; ++i) {
      int flat = i * 256 + tid;               // 14336 = 256c * 56w
      int c = flat / 56, w = flat - c * 56;
      float v = xb[(size_t)c * 3136 + w];
      t[w * 256 + (c ^ ((w & 31) << 3))] = (v > 0.f) ? 1 : ((v < 0.f) ? -1 : 0);
    }
    if (tid < 32) {   // zero cols 0 and 57
      int col = tid >> 4;
      *(v4i*)(rowp + (col ? 57 * 256 : 0) + (tid & 15) * 16) = (v4i){0, 0, 0, 0};
    }
    __syncthreads();
    int8_t* dst = rowp + 256;
    for (int i = 0; i < 7; ++i) {
      int f8 = i * 256 + tid;                 // 1792 8-byte chunks
      int w = f8 >> 5, c0 = (f8 & 31) << 3;
      uint2 v = *(const uint2*)&t[w * 256 + (c0 ^ ((w & 31) << 3))];
      *(uint2*)(dst + (size_t)w * 256 + c0) = v;
    }
    return;
  }

  if (blockIdx.x >= 512) {                    // ---- bias prep / zero sums ----
    const int pb = blockIdx.x - 512;
    if (pb == 32) {
      #pragma unroll
      for (int i = 0; i < 4; ++i) sums[i * 256 + tid] = 0ull;
      return;
    }
    float* zs = Wt;                           // reuse LDS (4KB)
    const int set = pb >> 4, o = pb & 15;
    const float* z = set ? z2 : z1;
    const float* W0 = set ? W02 : W01;
    int* bout = set ? b2 : b1;
    #pragma unroll
    for (int i = 0; i < 4; ++i) zs[i * 256 + tid] = z[(size_t)o * 1024 + i * 256 + tid];
    __syncthreads();
    const int j = tid >> 4, l = tid & 15;
    const float* wr = W0 + (size_t)j * 1024;
    double acc = 0.0;
    #pragma unroll 4
    for (int it = 0; it < 16; ++it) {
      float4 w4 = *(const float4*)&wr[it * 64 + l * 4];
      float4 z4 = *(const float4*)&zs[it * 64 + l * 4];
      acc += (double)w4.x * z4.x + (double)w4.y * z4.y + (double)w4.z * z4.z + (double)w4.w * z4.w;
    }
    #pragma unroll
    for (int m = 1; m < 16; m <<= 1) acc += __shfl_xor(acc, m, 64);
    if (l == 0) bout[o * 16 + j] = (acc > 0.0) ? 1 : ((acc < 0.0) ? -1 : 0);
    return;
  }

  // ---- hyper ----
  const int set = blockIdx.x >> 8;
  const int oi = blockIdx.x & 255;      // o*16+i
  const float* z = set ? z2 : z1;
  const float* W2 = set ? W22 : W21;
  const float* W3 = set ? W32 : W31;
  int8_t* Wb = set ? Wb2 : Wb1;

  if (tid < 16) *(float4*)&zsh[tid * 4] = ((const float4*)(z + (size_t)oi * 64))[tid];
  __syncthreads();

  // fc2: 8 chunks of 128 rows; thread (r=tid&127, half=tid>>7) does cols half*32..+31.
  {
    const int r = tid & 127, half = tid >> 7;
    for (int c = 0; c < 8; ++c) {
      if (c) __syncthreads();                 // combine of prev chunk done
      const float4* src = (const float4*)W2 + (size_t)c * 2048;
      #pragma unroll
      for (int i = 0; i < 8; ++i) {
        int G = i * 256 + tid;                // < 2048
        int row = G >> 4, g = G & 15;
        *(float4*)&Wt[row * 64 + (((g ^ row ^ (row >> 4)) & 15) << 2)] = src[G];
      }
      __syncthreads();
      double ax = 0, ay = 0, az = 0, aw = 0;
      double nx = 0, ny = 0, nz = 0, nw = 0;
      #pragma unroll
      for (int it = 0; it < 8; ++it) {
        int gi = half * 8 + it;
        float4 w4 = *(const float4*)&Wt[r * 64 + (((gi ^ r ^ (r >> 4)) & 15) << 2)];
        float4 z4 = *(const float4*)&zsh[gi * 4];
        ax += (double)w4.x * z4.x; ay += (double)w4.y * z4.y;
        az += (double)w4.z * z4.z; aw += (double)w4.w * z4.w;
        nx += (double)w4.x * w4.x; ny += (double)w4.y * w4.y;
        nz += (double)w4.z * w4.z; nw += (double)w4.w * w4.w;
      }
      pdot[tid] = (ax + ay) + (az + aw);
      pnrm[tid] = (nx + ny) + (nz + nw);
      __syncthreads();
      if (tid < 128) {
        double dot = pdot[tid] + pdot[tid + 128];
        double ss  = pnrm[tid] + pnrm[tid + 128];
        int j = c * 128 + tid;                // row index 0..1023 -> [q][e] padded 72
        hbuf[(j >> 6) * 72 + (j & 63)] = (float)(dot / sqrt(ss + 1e-6));
      }
    }
  }

  // fc3: W3 staged in 2 row-halves [72][64] (18.4KB); output (sub,k) computed in the
  // pass holding row jj = sub+16k. Single local f64 accumulator.
  {
    const int q = tid >> 4, sub = tid & 15;
    #pragma unroll
    for (int h = 0; h < 2; ++h) {
      __syncthreads();
      const float4* src = (const float4*)W3 + h * 1152;
      #pragma unroll
      for (int i = 0; i < 5; ++i) {
        int G = i * 256 + tid;
        if (G < 1152) {
          int lr = G >> 4, g = G & 15;
          *(float4*)&Wt[lr * 64 + (((g ^ lr ^ (lr >> 4)) & 15) << 2)] = src[G];
        }
      }
      __syncthreads();
      #pragma unroll
      for (int k = 0; k < 9; ++k) {
        int jj = sub + (k << 4);
        if (jj >= h * 72 && jj < h * 72 + 72) {
          int lr = jj - h * 72;
          double a = 0.0;
          #pragma unroll
          for (int it = 0; it < 16; ++it) {
            float4 w4 = *(const float4*)&Wt[lr * 64 + (((it ^ lr ^ (lr >> 4)) & 15) << 2)];
            float4 h4 = *(const float4*)&hbuf[q * 72 + it * 4];
            a += (double)w4.x * h4.x + (double)w4.y * h4.y
               + (double)w4.z * h4.z + (double)w4.w * h4.w;
          }
          int8_t sgn = (a > 0.0) ? (int8_t)1 : ((a < 0.0) ? (int8_t)(-1) : (int8_t)0);
          int tp = jj / 9, tap = jj - tp * 9;
          pk[tap * 256 + q * 16 + tp] = sgn;
        }
      }
    }
  }
  __syncthreads();

  // 144 coalesced 16B stores
  if (tid < 144) {
    const int tap = tid >> 4, qq = tid & 15;
    const int o = oi >> 4, ii = oi & 15;
    const int chunk = ((tap << 2) + (ii >> 2)) * 2 + ((ii >> 1) & 1);
    v4i val = *(const v4i*)&pk[tap * 256 + qq * 16];
    *(v4i*)(Wb + (size_t)chunk * 8192 + (size_t)(o * 16 + qq) * 32 + ((ii & 1) << 4)) = val;
  }
}

// ---------------- binarized 3x3 conv via i8 MFMA implicit GEMM ----------------
// grid (28,16), block 512 = 8 waves (pxgrp 0-1 x cogrp 0-3). Tile 112 px x 256 co.
// Per wave: 2 px-frags x 2 co-halves -> acc 64 AGPR; A depth-1 prefetch.
// MODE 1 computes BN1 thresholds per-block from sumsIn. XCD-swizzled.

template <int MODE>
__global__ __launch_bounds__(512, 4) void conv_kernel(
    const int8_t* __restrict__ Sp, const int16_t* __restrict__ rawin,
    const unsigned long long* __restrict__ sumsIn,
    const float* __restrict__ gamma, const float* __restrict__ beta,
    const int8_t* __restrict__ WbP, const int* __restrict__ bias,
    int16_t* __restrict__ raw, unsigned long long* __restrict__ sumsOut)
{
  __shared__ __align__(16) int8_t lds[59392];   // 232 pp-rows x 256B
  __shared__ float thrS[256];
  __shared__ int sfS[256];
  const int tid = threadIdx.x;
  const int lane = tid & 63;
  const int f0 = blockIdx.x + 28 * blockIdx.y;      // [0,448)
  const int orig = (f0 & 7) * 56 + (f0 >> 3);       // 448 = 8*56; xcd gets 2 images
  const int b = orig / 28, bx = orig % 28;
  const int H0 = bx << 1;             // output rows H0, H0+1

  const int n = lane & 31, kg = lane >> 5;
  const int wid = tid >> 6;
  const int cogrp = wid & 3, pxgrp = wid >> 2;

  if (MODE == 1) {                    // per-block BN1 threshold compute
    if (tid < 256) {
      double S = (double)(long long)sumsIn[tid];
      double Q = (double)(long long)sumsIn[256 + tid];
      double mean = S / 50176.0;
      double var = Q / 50176.0 - mean * mean;
      double istd = 1.0 / sqrt(var + 1e-5);
      double A = (double)gamma[tid] * istd;
      float Af = (float)A;
      float thr; int sf;
      if (Af > 0.f)      { thr = (float)(mean - (double)beta[tid] / A); sf = 1; }
      else if (Af < 0.f) { thr = (float)(mean - (double)beta[tid] / A); sf = -1; }
      else               { thr = -1e30f; sf = (beta[tid] > 0.f) ? 1 : ((beta[tid] < 0.f) ? -1 : 0); }
      thrS[tid] = thr; sfS[tid] = sf;
    }
    __syncthreads();
  }

  // ---- A prologue: chunk 0 into buf 0 ----
  const int8_t* Abase = WbP + (size_t)((cogrp << 6) + n) * 32 + (kg << 4);
  v4i Ar[2][2][2];   // [buf][c2][a]
  #pragma unroll
  for (int c2 = 0; c2 < 2; ++c2)
    #pragma unroll
    for (int a = 0; a < 2; ++a)
      Ar[0][c2][a] = *(const v4i*)(Abase + (size_t)c2 * 8192 + a * 1024);

  // ---- stage input tile: 232 pp x 16 granules, XOR-swizzled by col&7 ----
  if (MODE == 0) {
    const int8_t* SpB = Sp + ((size_t)b * 58 + H0) * 58 * 256;
    #pragma unroll
    for (int ph = 0; ph < 2; ++ph) {          // 2 phases x 4 loads
      v4i tmp[4];
      #pragma unroll
      for (int it = 0; it < 4; ++it) {
        int G = (ph * 4 + it) * 512 + tid;
        if (G < 3712) {
          int pp = G >> 4, gl = G & 15;
          int wp = pp % 58;
          tmp[it] = *(const v4i*)(SpB + pp * 256 + ((gl ^ (wp & 7)) << 4));
        }
      }
      #pragma unroll
      for (int it = 0; it < 4; ++it) {
        int G = (ph * 4 + it) * 512 + tid;
        if (G < 3712) *(v4i*)(lds + (G << 4)) = tmp[it];
      }
    }
  } else {
    // threshold-binarize from raw i16: thread owns fixed ci-granule gsrc
    const int gsrc = tid & 15;
    const int ppt = tid >> 4;                 // 0..31
    float thr[16]; int sf[16];
    #pragma unroll
    for (int j = 0; j < 16; ++j) { thr[j] = thrS[gsrc * 16 + j]; sf[j] = sfS[gsrc * 16 + j]; }
    #pragma unroll
    for (int it = 0; it < 8; ++it) {
      int pp = it * 32 + ppt;
      if (pp < 232) {
        int prow = pp / 58, pcol = pp - prow * 58;
        int ir = H0 + prow - 1, ic = pcol - 1;
        v4i outv = (v4i){0, 0, 0, 0};
        if (ir >= 0 && ir <= 55 && ic >= 0 && ic <= 55) {
          const int16_t* src = rawin + ((size_t)(b * 3136 + ir * 56 + ic)) * 256 + gsrc * 16;
          v4i lo = *(const v4i*)src;
          v4i hi = *(const v4i*)(src + 8);
          #pragma unroll
          for (int j = 0; j < 16; ++j) {
            int wd = (j < 8) ? lo[(j >> 1) & 3] : hi[(j >> 1) & 3];
            int v = (j & 1) ? (wd >> 16) : (int)(short)wd;
            float fv = (float)v;
            int bj = (fv > thr[j]) ? sf[j] : ((fv < thr[j]) ? -sf[j] : 0);
            outv[j >> 2] |= (bj & 0xff) << ((j & 3) << 3);
          }
        }
        *(v4i*)(lds + ((pp << 4) + (gsrc ^ (pcol & 7))) * 16) = outv;
      }
    }
  }

  int pixoff[2], wcol[2];
  #pragma unroll
  for (int f = 0; f < 2; ++f) {
    int px = (((pxgrp << 1) + f) << 5) + n;
    if (px > 111) px = 111;       // wid=7,f=1,n>=16: clamped duplicate (not stored)
    int hh = px / 56, ww = px - hh * 56;
    pixoff[f] = hh * 58 + ww;
    wcol[f] = ww;
  }

  v16i acc[2][2];
  #pragma unroll
  for (int f = 0; f < 2; ++f)
    #pragma unroll
    for (int a = 0; a < 2; ++a)
      #pragma unroll
      for (int e = 0; e < 16; ++e) acc[f][a][e] = 0;

  __syncthreads();

  #pragma unroll
  for (int ks = 0; ks < 36; ++ks) {
    const int cur = ks & 1;
    if (ks + 1 < 36) {                    // depth-1 prefetch
      #pragma unroll
      for (int c2 = 0; c2 < 2; ++c2)
        #pragma unroll
        for (int a = 0; a < 2; ++a)
          Ar[cur ^ 1][c2][a] = *(const v4i*)(Abase + (size_t)((ks + 1) * 2 + c2) * 8192 + a * 1024);
    }
    const int tap = ks >> 2, c64 = ks & 3;
    const int r = tap / 3, s = tap - 3 * (tap / 3);
    #pragma unroll
    for (int c2 = 0; c2 < 2; ++c2) {
      v4i Af0 = Ar[cur][c2][0], Af1 = Ar[cur][c2][1];
      #pragma unroll
      for (int f = 0; f < 2; ++f) {
        const int gb = (c64 << 2) + (c2 << 1) + kg;
        v4i Bf = *(const v4i*)(lds + ((pixoff[f] + r * 58 + s) << 8)
                               + ((gb ^ ((wcol[f] + s) & 7)) << 4));
        acc[f][0] = __builtin_amdgcn_mfma_i32_32x32x32_i8(Af0, Bf, acc[f][0], 0, 0, 0);
        acc[f][1] = __builtin_amdgcn_mfma_i32_32x32x32_i8(Af1, Bf, acc[f][1], 0, 0, 0);
      }
    }
  }

  // ---- epilogue: acc+bias -> LDS repack (swizzled) -> coalesced stores + stats ----
  __syncthreads();                 // B-tile dead; reuse LDS
  #pragma unroll
  for (int f = 0; f < 2; ++f) {
    int px = (((pxgrp << 1) + f) << 5) + n;
    if (px < 112) {
      #pragma unroll
      for (int a = 0; a < 2; ++a) {
        #pragma unroll
        for (int q = 0; q < 4; ++q) {
          int co = (cogrp << 6) + (a << 5) + (q << 3) + (kg << 2);
          v4i bi = *(const v4i*)(bias + co);
          short4 o;
          o.x = (short)(acc[f][a][q * 4 + 0] + bi.x);
          o.y = (short)(acc[f][a][q * 4 + 1] + bi.y);
          o.z = (short)(acc[f][a][q * 4 + 2] + bi.z);
          o.w = (short)(acc[f][a][q * 4 + 3] + bi.w);
          int g = co >> 3;          // 0..31
          *(short4*)(lds + px * 512 + ((g ^ (px & 31)) << 4) + (kg << 3)) = o;
        }
      }
    }
  }
  __syncthreads();
  const int pbase = b * 3136 + bx * 112;
  const int gg = tid & 31;
  int s8[8], q8[8];
  #pragma unroll
  for (int j = 0; j < 8; ++j) { s8[j] = 0; q8[j] = 0; }
  #pragma unroll
  for (int i = 0; i < 7; ++i) {
    int rrow = i * 16 + (tid >> 5);
    v4i val = *(const v4i*)(lds + rrow * 512 + ((gg ^ (rrow & 31)) << 4));
    *(v4i*)(raw + (size_t)(pbase + rrow) * 256 + gg * 8) = val;
    #pragma unroll
    for (int j = 0; j < 8; ++j) {
      int wd = val[j >> 1];
      int v = (j & 1) ? (wd >> 16) : (int)(short)wd;
      s8[j] += v; q8[j] += v * v;
    }
  }
  __syncthreads();                 // done reading repack area
  int* red = (int*)lds;            // [0:4096) sums, [4096:8192) sq
  #pragma unroll
  for (int j = 0; j < 8; ++j) { red[tid * 8 + j] = s8[j]; red[4096 + tid * 8 + j] = q8[j]; }
  __syncthreads();
  if (tid < 256) {
    const int ch = tid;            // 256 channels
    const int own = ch >> 3, sub = ch & 7;
    long long S = 0, Q = 0;
    #pragma unroll
    for (int jj = 0; jj < 16; ++jj) {
      int t2 = own + 32 * jj;
      S += red[t2 * 8 + sub];
      Q += red[4096 + t2 * 8 + sub];
    }
    atomicAdd(&sumsOut[ch], (unsigned long long)S);
    atomicAdd(&sumsOut[256 + ch], (unsigned long long)Q);
  }
}

// ---------------- final: BN2 (params computed in-block) + residual, NHWC -> NCHW ----------------
// grid (56,16) remapped so xcd = b/2 (raw2 rows L2-local from conv2).

__global__ void final_kernel(const int16_t* __restrict__ raw2,
                             const unsigned long long* __restrict__ sums2,
                             const float* __restrict__ gamma, const float* __restrict__ beta,
                             const float* __restrict__ x, float* __restrict__ out) {
  __shared__ float t[256 * 57];
  __shared__ __align__(16) float mS[256], AS[256], bS[256];
  const int tid = threadIdx.x;
  const int f0 = blockIdx.x + 56 * blockIdx.y;      // [0,896)
  const int orig = (f0 & 7) * 112 + (f0 >> 3);      // 896 = 8*112
  const int b = orig / 56, h = orig % 56;
  const int rowp = b * 3136 + h * 56;
  {
    double S = (double)(long long)sums2[tid];
    double Q = (double)(long long)sums2[256 + tid];
    double mean = S / 50176.0;
    double var = Q / 50176.0 - mean * mean;
    double istd = 1.0 / sqrt(var + 1e-5);
    mS[tid] = (float)mean;
    AS[tid] = gamma[tid] * (float)istd;
    bS[tid] = beta[tid];
  }
  __syncthreads();
  for (int i = 0; i < 7; ++i) {
    int f8 = i * 256 + tid;
    int px = f8 >> 5, c0 = (f8 & 31) << 3;
    float m[8], A[8], bb[8];
    *(float4*)&m[0]  = *(const float4*)&mS[c0];
    *(float4*)&m[4]  = *(const float4*)&mS[c0 + 4];
    *(float4*)&A[0]  = *(const float4*)&AS[c0];
    *(float4*)&A[4]  = *(const float4*)&AS[c0 + 4];
    *(float4*)&bb[0] = *(const float4*)&bS[c0];
    *(float4*)&bb[4] = *(const float4*)&bS[c0 + 4];
    v4i vv = *(const v4i*)(raw2 + (size_t)(rowp + px) * 256 + c0);
    #pragma unroll
    for (int j = 0; j < 8; ++j) {
      int wd = vv[j >> 1];
      int v = (j & 1) ? (wd >> 16) : (int)(short)wd;
      t[(c0 + j) * 57 + px] = ((float)v - m[j]) * A[j] + bb[j];
    }
  }
  __syncthreads();
  const float* xb = x + (size_t)b * 802816 + (size_t)h * 56;
  float* ob = out + (size_t)b * 802816 + (size_t)h * 56;
  for (int i = 0; i < 16; ++i) {
    int idx = i * 256 + tid;            // 256c x 16 slots (14 valid)
    int c = idx >> 4, wq = idx & 15;
    if (wq < 14) {
      int w0 = wq * 4;
      float4 xv = *(const float4*)(xb + (size_t)c * 3136 + w0);
      float4 o;
      o.x = t[c * 57 + w0 + 0] + xv.x;
      o.y = t[c * 57 + w0 + 1] + xv.y;
      o.z = t[c * 57 + w0 + 2] + xv.z;
      o.w = t[c * 57 + w0 + 3] + xv.w;
      *(float4*)(ob + (size_t)c * 3136 + w0) = o;
    }
  }
}

// ---------------- host launcher ----------------

extern "C" void kernel_launch(void* const* d_in, const int* in_sizes, int n_in,
                              void* d_out, int out_size, void* d_ws, size_t ws_size,
                              hipStream_t stream) {
  const float* x      = (const float*)d_in[0];
  const float* z1     = (const float*)d_in[1];
  const float* W0_1   = (const float*)d_in[2];
  const float* W2_1   = (const float*)d_in[3];
  const float* W3_1   = (const float*)d_in[4];
  const float* gamma1 = (const float*)d_in[5];
  const float* beta1  = (const float*)d_in[6];
  const float* z2     = (const float*)d_in[7];
  const float* W0_2   = (const float*)d_in[8];
  const float* W2_2   = (const float*)d_in[9];
  const float* W3_2   = (const float*)d_in[10];
  const float* gamma2 = (const float*)d_in[11];
  const float* beta2  = (const float*)d_in[12];
  float* out = (float*)d_out;

  char* ws = (char*)d_ws;
  size_t off = 0;
  auto alloc = [&](size_t sz) -> void* {
    void* p = ws + off;
    off += (sz + 255) & ~(size_t)255;
    return p;
  };
  int8_t* Sp1   = (int8_t*)alloc(13778944);          // 16*58*58*256
  int16_t* raw1 = (int16_t*)alloc(25690112);         // 50176*256*2
  int16_t* raw2 = (int16_t*)alloc(25690112);
  int8_t* Wb1   = (int8_t*)alloc(589824);
  int8_t* Wb2   = (int8_t*)alloc(589824);
  int* b1       = (int*)alloc(1024);
  int* b2       = (int*)alloc(1024);
  unsigned long long* sums = (unsigned long long*)alloc(8192); // sums1 | sums2
  if (ws_size < off) return;

  fused_pre_kernel<<<1473, 256, 0, stream>>>(z1, W2_1, W3_1, z2, W2_2, W3_2, Wb1, Wb2,
                                             W0_1, W0_2, b1, b2, sums, x, Sp1);
  conv_kernel<0><<<dim3(28, 16), 512, 0, stream>>>(Sp1, nullptr, nullptr, nullptr, nullptr,
                                                   Wb1, b1, raw1, sums);
  conv_kernel<1><<<dim3(28, 16), 512, 0, stream>>>(nullptr, raw1, sums, gamma1, beta1,
                                                   Wb2, b2, raw2, sums + 512);
  final_kernel<<<dim3(56, 16), 256, 0, stream>>>(raw2, sums + 512, gamma2, beta2, x, out);
}